// Round 2
// baseline (16830.522 us; speedup 1.0000x reference)
//
#include <hip/hip_runtime.h>
#include <cstdint>
#include <cstddef>

#define T_ 512
#define B_ 64
#define I_ 512
#define H_ 512

typedef __attribute__((ext_vector_type(8))) short short8;
typedef __attribute__((ext_vector_type(4))) float f32x4;

#define MFMA(a, b, c) __builtin_amdgcn_mfma_f32_16x16x32_bf16((a), (b), (c), 0, 0, 0)

__device__ __forceinline__ unsigned short f2bf(float f) {
  union { float f; unsigned u; } v; v.f = f;
  unsigned r = v.u + 0x7fffu + ((v.u >> 16) & 1u);
  return (unsigned short)(r >> 16);
}

__device__ __forceinline__ float sigm(float x) { return 1.0f / (1.0f + __expf(-x)); }

__device__ __forceinline__ short8 loadWfrag(const float* __restrict__ p) {
  float4 a = ((const float4*)p)[0];
  float4 b = ((const float4*)p)[1];
  short8 r;
  r[0] = (short)f2bf(a.x); r[1] = (short)f2bf(a.y);
  r[2] = (short)f2bf(a.z); r[3] = (short)f2bf(a.w);
  r[4] = (short)f2bf(b.x); r[5] = (short)f2bf(b.y);
  r[6] = (short)f2bf(b.z); r[7] = (short)f2bf(b.w);
  return r;
}

// ---- prep: convert X (T,B,I) fp32 -> bf16 in ws. 16384x256 threads, 1 float4 each.
__global__ void prep_x(const float4* __restrict__ x, ushort4* __restrict__ xb) {
  int i = blockIdx.x * 256 + threadIdx.x;
  float4 v = x[i];
  ushort4 o;
  o.x = f2bf(v.x); o.y = f2bf(v.y); o.z = f2bf(v.z); o.w = f2bf(v.w);
  xb[i] = o;
}

// ---- prep: h0 -> bf16 parity-0 buffers, zero flags. 256x256 threads.
__global__ void prep_init(const float* __restrict__ h0f, const float* __restrict__ h0b,
                          unsigned short* __restrict__ hbufs, int* __restrict__ flags) {
  int i = blockIdx.x * 256 + threadIdx.x;
  if (i < 32768) {
    hbufs[i] = f2bf(h0f[i]);                    // dir0, parity0
  } else {
    int j = i - 32768;
    hbufs[2 * 32768 + j] = f2bf(h0b[j]);        // dir1, parity0
  }
  if (i < 128) flags[i] = 0;
}

// ---- persistent bidirectional LSTM. grid=128 (64 WGs/dir), block=256.
// NOTE: regular launch. 128 blocks with __launch_bounds__(256,1) are
// capacity-guaranteed co-resident on 256 CUs (>=1 block/CU), so the
// flag-based producer/consumer protocol cannot deadlock.
__global__ __launch_bounds__(256, 1) void lstm_coop(
    const unsigned short* __restrict__ xbf,
    unsigned short* __restrict__ hbufs,
    int* __restrict__ flags,
    const float* __restrict__ Wih_f, const float* __restrict__ Whh_f,
    const float* __restrict__ bih_f, const float* __restrict__ bhh_f,
    const float* __restrict__ c0_f,
    const float* __restrict__ Wih_b, const float* __restrict__ Whh_b,
    const float* __restrict__ bih_b, const float* __restrict__ bhh_b,
    const float* __restrict__ c0_b,
    float* __restrict__ out) {
  __shared__ uint4 stage[4096];  // 64 KiB: staging for x_t / h (XOR-swizzled), reused for gates

  const int tid = threadIdx.x;
  const int wave = tid >> 6;
  const int lane = tid & 63;
  const int quad = lane >> 4;
  const int lm = lane & 15;

  const int wg = blockIdx.x;
  const int dir = wg >> 6;       // 0 = forward, 1 = backward
  const int jw = wg & 63;        // hidden-slice index
  const int hb = jw * 8;         // first hidden unit owned

  const float* Wih = dir ? Wih_b : Wih_f;
  const float* Whh = dir ? Whh_b : Whh_f;
  const float* bih = dir ? bih_b : bih_f;
  const float* bhh = dir ? bhh_b : bhh_f;
  const float* c0  = dir ? c0_b  : c0_f;

  // ---- weight fragments: 32 gate rows x K=512, both matrices, in registers ----
  short8 wx[2][16], wh[2][16];
#pragma unroll
  for (int nt = 0; nt < 2; ++nt) {
    int nl = nt * 16 + lm;                         // local gate-row 0..31
    int row = (nl >> 3) * 512 + hb + (nl & 7);     // global row in (4H, 512)
#pragma unroll
    for (int kk = 0; kk < 16; ++kk) {
      int k = kk * 32 + quad * 8;
      wx[nt][kk] = loadWfrag(Wih + (size_t)row * 512 + k);
      wh[nt][kk] = loadWfrag(Whh + (size_t)row * 512 + k);
    }
  }

  // ---- epilogue ownership: thread -> (m = tid>>2, u0 = 2*(tid&3)), 2 items ----
  const int me = tid >> 2;
  const int u0 = 2 * (tid & 3);
  float bsum[4][2];
#pragma unroll
  for (int g = 0; g < 4; ++g)
#pragma unroll
    for (int rep = 0; rep < 2; ++rep) {
      int col = g * 512 + hb + u0 + rep;
      bsum[g][rep] = bih[col] + bhh[col];
    }
  float creg[2];
  creg[0] = c0[(size_t)me * 512 + hb + u0];
  creg[1] = c0[(size_t)me * 512 + hb + u0 + 1];
  float hlast[2] = {0.f, 0.f};

  unsigned short* hb0 = hbufs + (size_t)(dir * 2) * 32768;  // parity buffers for my dir
  int* myflags = flags + dir * 64;
  float* gf = (float*)stage;  // gates overlay, pitch 33 floats

  for (int s = 0; s < 512; ++s) {
    const int t = dir ? (511 - s) : s;

    // ---- stage x_t (64 KB contiguous bf16) into LDS, swizzled ----
    const uint4* xsrc = (const uint4*)xbf + (size_t)t * 4096;
#pragma unroll
    for (int it = 0; it < 16; ++it) {
      int g = tid + it * 256;
      int m = g >> 6, c = g & 63;
      stage[m * 64 + (c ^ (m & 7))] = xsrc[g];
    }
    __syncthreads();

    // ---- x-phase MFMAs (overlaps the h-wait below across WGs) ----
    f32x4 acc0 = {0.f, 0.f, 0.f, 0.f};
    f32x4 acc1 = {0.f, 0.f, 0.f, 0.f};
    {
      const int arow = wave * 16 + lm;
      const int abase = arow * 64;
      const int ax = arow & 7;
#pragma unroll
      for (int kk = 0; kk < 16; ++kk) {
        short8 a = __builtin_bit_cast(short8, stage[abase + ((kk * 4 + quad) ^ ax)]);
        acc0 = MFMA(a, wx[0][kk], acc0);
        acc1 = MFMA(a, wx[1][kk], acc1);
      }
    }

    // ---- wait for h^(s): all 64 producer flags of my direction >= s ----
    if (tid < 64) {
      while (__hip_atomic_load(&myflags[tid], __ATOMIC_RELAXED, __HIP_MEMORY_SCOPE_AGENT) < s)
        __builtin_amdgcn_s_sleep(2);
    }
    __syncthreads();
    __threadfence();  // acquire: invalidate stale L1/L2 before reading fresh h

    // ---- stage h^(s) ----
    const uint4* hsrc = (const uint4*)(hb0 + (size_t)(s & 1) * 32768);
#pragma unroll
    for (int it = 0; it < 16; ++it) {
      int g = tid + it * 256;
      int m = g >> 6, c = g & 63;
      stage[m * 64 + (c ^ (m & 7))] = hsrc[g];
    }
    __syncthreads();

    // ---- h-phase MFMAs ----
    {
      const int arow = wave * 16 + lm;
      const int abase = arow * 64;
      const int ax = arow & 7;
#pragma unroll
      for (int kk = 0; kk < 16; ++kk) {
        short8 a = __builtin_bit_cast(short8, stage[abase + ((kk * 4 + quad) ^ ax)]);
        acc0 = MFMA(a, wh[0][kk], acc0);
        acc1 = MFMA(a, wh[1][kk], acc1);
      }
    }
    __syncthreads();  // all stage reads done; reuse LDS for gates

    // ---- gates to LDS: D layout col=lane&15, row=quad*4+reg ----
#pragma unroll
    for (int r = 0; r < 4; ++r) {
      int row = wave * 16 + quad * 4 + r;
      gf[row * 33 + lm] = acc0[r];
      gf[row * 33 + 16 + lm] = acc1[r];
    }
    __syncthreads();

    // ---- epilogue: c/h update for (me, u0), (me, u0+1) ----
    unsigned short* hdst = hb0 + (size_t)((s + 1) & 1) * 32768;
    float hv[2];
#pragma unroll
    for (int rep = 0; rep < 2; ++rep) {
      int u = u0 + rep;
      float gi = gf[me * 33 + u]      + bsum[0][rep];
      float gfr = gf[me * 33 + 8 + u] + bsum[1][rep];
      float gg = gf[me * 33 + 16 + u] + bsum[2][rep];
      float go = gf[me * 33 + 24 + u] + bsum[3][rep];
      float cn = sigm(gfr) * creg[rep] + sigm(gi) * tanhf(gg);
      creg[rep] = cn;
      hv[rep] = sigm(go) * tanhf(cn);
    }
    // h slice (bf16, packed 2 -> 4B store) and output slice (fp32, float2 store)
    unsigned hpack = (unsigned)f2bf(hv[0]) | ((unsigned)f2bf(hv[1]) << 16);
    *(unsigned*)(hdst + (size_t)me * 512 + hb + u0) = hpack;
    float2 ov; ov.x = hv[0]; ov.y = hv[1];
    *(float2*)(out + (size_t)t * 65536 + (size_t)me * 1024 + dir * 512 + hb + u0) = ov;
    hlast[0] = hv[0]; hlast[1] = hv[1];

    __threadfence();   // release: make h slice visible device-wide
    __syncthreads();   // all threads' stores done before flag
    if (tid == 0)
      __hip_atomic_store(&myflags[jw], s + 1, __ATOMIC_RELEASE, __HIP_MEMORY_SCOPE_AGENT);
  }

  // ---- final hT, cT ----
  float* obase = out + 33554432 + dir * 65536;
  float2 hvf; hvf.x = hlast[0]; hvf.y = hlast[1];
  float2 cvf; cvf.x = creg[0];  cvf.y = creg[1];
  *(float2*)(obase + (size_t)me * 512 + hb + u0) = hvf;
  *(float2*)(obase + 32768 + (size_t)me * 512 + hb + u0) = cvf;
}

extern "C" void kernel_launch(void* const* d_in, const int* in_sizes, int n_in,
                              void* d_out, int out_size, void* d_ws, size_t ws_size,
                              hipStream_t stream) {
  (void)in_sizes; (void)n_in; (void)out_size; (void)ws_size;

  const float* X     = (const float*)d_in[0];
  const float* h0_f  = (const float*)d_in[1];
  const float* c0_f  = (const float*)d_in[2];
  const float* h0_b  = (const float*)d_in[3];
  const float* c0_b  = (const float*)d_in[4];
  const float* Wih_f = (const float*)d_in[5];
  const float* Whh_f = (const float*)d_in[6];
  const float* bih_f = (const float*)d_in[7];
  const float* bhh_f = (const float*)d_in[8];
  const float* Wih_b = (const float*)d_in[9];
  const float* Whh_b = (const float*)d_in[10];
  const float* bih_b = (const float*)d_in[11];
  const float* bhh_b = (const float*)d_in[12];
  float* out = (float*)d_out;

  unsigned short* xbf   = (unsigned short*)d_ws;                         // 33,554,432 B
  unsigned short* hbufs = (unsigned short*)((char*)d_ws + 33554432);     //    262,144 B
  int* flags            = (int*)((char*)d_ws + 33554432 + 262144);       //        512 B

  prep_x<<<16384, 256, 0, stream>>>((const float4*)X, (ushort4*)xbf);
  prep_init<<<256, 256, 0, stream>>>(h0_f, h0_b, hbufs, flags);

  lstm_coop<<<dim3(128), dim3(256), 0, stream>>>(
      xbf, hbufs, flags,
      Wih_f, Whh_f, bih_f, bhh_f, c0_f,
      Wih_b, Whh_b, bih_b, bhh_b, c0_b,
      out);
}

// Round 3
// 4182.930 us; speedup vs baseline: 4.0236x; 4.0236x over previous
//
#include <hip/hip_runtime.h>
#include <cstdint>
#include <cstddef>

#define T_ 512
#define B_ 64
#define I_ 512
#define H_ 512

typedef __attribute__((ext_vector_type(8))) short short8;
typedef __attribute__((ext_vector_type(4))) float f32x4;

#define MFMA(a, b, c) __builtin_amdgcn_mfma_f32_16x16x32_bf16((a), (b), (c), 0, 0, 0)

__device__ __forceinline__ unsigned short f2bf(float f) {
  union { float f; unsigned u; } v; v.f = f;
  unsigned r = v.u + 0x7fffu + ((v.u >> 16) & 1u);
  return (unsigned short)(r >> 16);
}

__device__ __forceinline__ float sigm(float x) { return 1.0f / (1.0f + __expf(-x)); }
__device__ __forceinline__ float tanh_fast(float x) {
  float e = __expf(2.0f * x);
  return 1.0f - 2.0f / (e + 1.0f);
}

__device__ __forceinline__ short8 loadWfrag(const float* __restrict__ p) {
  float4 a = ((const float4*)p)[0];
  float4 b = ((const float4*)p)[1];
  short8 r;
  r[0] = (short)f2bf(a.x); r[1] = (short)f2bf(a.y);
  r[2] = (short)f2bf(a.z); r[3] = (short)f2bf(a.w);
  r[4] = (short)f2bf(b.x); r[5] = (short)f2bf(b.y);
  r[6] = (short)f2bf(b.z); r[7] = (short)f2bf(b.w);
  return r;
}

// ---- prep: convert X (T,B,I) fp32 -> bf16 in ws. 16384x256 threads, 1 float4 each.
__global__ void prep_x(const float4* __restrict__ x, ushort4* __restrict__ xb) {
  int i = blockIdx.x * 256 + threadIdx.x;
  float4 v = x[i];
  ushort4 o;
  o.x = f2bf(v.x); o.y = f2bf(v.y); o.z = f2bf(v.z); o.w = f2bf(v.w);
  xb[i] = o;
}

// ---- prep: h0 -> bf16 parity-0 buffers, zero flags. 256x256 threads.
__global__ void prep_init(const float* __restrict__ h0f, const float* __restrict__ h0b,
                          unsigned short* __restrict__ hbufs, int* __restrict__ flags) {
  int i = blockIdx.x * 256 + threadIdx.x;
  if (i < 32768) {
    hbufs[i] = f2bf(h0f[i]);                    // dir0, parity0
  } else {
    int j = i - 32768;
    hbufs[2 * 32768 + j] = f2bf(h0b[j]);        // dir1, parity0
  }
  if (i < 128) flags[i] = 0;
}

// ---- persistent bidirectional LSTM. grid=128 (64 WGs/dir), block=256.
// Regular launch: 128 blocks @ __launch_bounds__(256,1) are capacity-guaranteed
// co-resident on 256 CUs, so the flag protocol cannot deadlock.
// Coherence: h + flags move via sc1 (agent-scope relaxed atomic) stores/loads —
// write-through to the coherent point, L2-bypass on read. NO __threadfence():
// avoids per-step buffer_wbl2/buffer_inv (full-L2 writeback+invalidate), which
// was the R2 bottleneck, and keeps staged X resident in each XCD's L2.
__global__ __launch_bounds__(256, 1) void lstm_coop(
    const unsigned short* __restrict__ xbf,
    unsigned short* __restrict__ hbufs,
    int* __restrict__ flags,
    const float* __restrict__ Wih_f, const float* __restrict__ Whh_f,
    const float* __restrict__ bih_f, const float* __restrict__ bhh_f,
    const float* __restrict__ c0_f,
    const float* __restrict__ Wih_b, const float* __restrict__ Whh_b,
    const float* __restrict__ bih_b, const float* __restrict__ bhh_b,
    const float* __restrict__ c0_b,
    float* __restrict__ out) {
  __shared__ uint4 stage[4096];  // 64 KiB: x_t / h staging (XOR-swizzled); gates overlay

  const int tid = threadIdx.x;
  const int wave = tid >> 6;
  const int lane = tid & 63;
  const int quad = lane >> 4;
  const int lm = lane & 15;

  const int wg = blockIdx.x;
  const int dir = wg >> 6;       // 0 = forward, 1 = backward
  const int jw = wg & 63;        // hidden-slice index
  const int hb = jw * 8;         // first hidden unit owned

  const float* Wih = dir ? Wih_b : Wih_f;
  const float* Whh = dir ? Whh_b : Whh_f;
  const float* bih = dir ? bih_b : bih_f;
  const float* bhh = dir ? bhh_b : bhh_f;
  const float* c0  = dir ? c0_b  : c0_f;

  // ---- weight fragments: 32 gate rows x K=512, both matrices, in registers ----
  short8 wx[2][16], wh[2][16];
#pragma unroll
  for (int nt = 0; nt < 2; ++nt) {
    int nl = nt * 16 + lm;                         // local gate-row 0..31
    int row = (nl >> 3) * 512 + hb + (nl & 7);     // global row in (4H, 512)
#pragma unroll
    for (int kk = 0; kk < 16; ++kk) {
      int k = kk * 32 + quad * 8;
      wx[nt][kk] = loadWfrag(Wih + (size_t)row * 512 + k);
      wh[nt][kk] = loadWfrag(Whh + (size_t)row * 512 + k);
    }
  }

  // ---- epilogue ownership: thread -> (me = tid>>2, u0 = 2*(tid&3)), 2 items ----
  const int me = tid >> 2;
  const int u0 = 2 * (tid & 3);
  float bsum[4][2];
#pragma unroll
  for (int g = 0; g < 4; ++g)
#pragma unroll
    for (int rep = 0; rep < 2; ++rep) {
      int col = g * 512 + hb + u0 + rep;
      bsum[g][rep] = bih[col] + bhh[col];
    }
  float creg[2];
  creg[0] = c0[(size_t)me * 512 + hb + u0];
  creg[1] = c0[(size_t)me * 512 + hb + u0 + 1];
  float hlast[2] = {0.f, 0.f};

  unsigned short* hb0 = hbufs + (size_t)(dir * 2) * 32768;  // parity buffers for my dir
  int* myflags = flags + dir * 64;
  float* gf = (float*)stage;  // gates overlay, pitch 33 floats

  for (int s = 0; s < 512; ++s) {
    const int t = dir ? (511 - s) : s;

    // ---- stage x_t (64 KB contiguous bf16) into LDS, swizzled (plain, L2-cached) ----
    const uint4* xsrc = (const uint4*)xbf + (size_t)t * 4096;
#pragma unroll
    for (int it = 0; it < 16; ++it) {
      int g = tid + it * 256;
      int m = g >> 6, c = g & 63;
      stage[m * 64 + (c ^ (m & 7))] = xsrc[g];
    }
    __syncthreads();                                   // #1 x staged

    // ---- wait for h^(s): lane i of wave 0 spins on producer i's flag ----
    if (tid < 64) {
      while (__hip_atomic_load(&myflags[tid], __ATOMIC_RELAXED, __HIP_MEMORY_SCOPE_AGENT) < s)
        __builtin_amdgcn_s_sleep(1);
    }
    __syncthreads();                                   // #2 h is at coherent point

    // ---- issue h loads (sc1: bypass stale L2), x-MFMAs fill their shadow ----
    const unsigned long long* hsrc =
        (const unsigned long long*)(hb0 + (size_t)(s & 1) * 32768);
    unsigned long long hreg[32];
#pragma unroll
    for (int it = 0; it < 16; ++it) {
      int g = tid + it * 256;
      hreg[2 * it]     = __hip_atomic_load(hsrc + 2 * g,     __ATOMIC_RELAXED, __HIP_MEMORY_SCOPE_AGENT);
      hreg[2 * it + 1] = __hip_atomic_load(hsrc + 2 * g + 1, __ATOMIC_RELAXED, __HIP_MEMORY_SCOPE_AGENT);
    }

    f32x4 acc0 = {0.f, 0.f, 0.f, 0.f};
    f32x4 acc1 = {0.f, 0.f, 0.f, 0.f};
    {
      const int arow = wave * 16 + lm;
      const int abase = arow * 64;
      const int ax = arow & 7;
#pragma unroll
      for (int kk = 0; kk < 16; ++kk) {
        short8 a = __builtin_bit_cast(short8, stage[abase + ((kk * 4 + quad) ^ ax)]);
        acc0 = MFMA(a, wx[0][kk], acc0);
        acc1 = MFMA(a, wx[1][kk], acc1);
      }
    }
    __syncthreads();                                   // #3 all x ds_reads done

    // ---- stage h^(s) from registers ----
#pragma unroll
    for (int it = 0; it < 16; ++it) {
      int g = tid + it * 256;
      int m = g >> 6, c = g & 63;
      uint4 v;
      v.x = (unsigned)(hreg[2 * it]);
      v.y = (unsigned)(hreg[2 * it] >> 32);
      v.z = (unsigned)(hreg[2 * it + 1]);
      v.w = (unsigned)(hreg[2 * it + 1] >> 32);
      stage[m * 64 + (c ^ (m & 7))] = v;
    }
    __syncthreads();                                   // #4 h staged

    // ---- h-phase MFMAs ----
    {
      const int arow = wave * 16 + lm;
      const int abase = arow * 64;
      const int ax = arow & 7;
#pragma unroll
      for (int kk = 0; kk < 16; ++kk) {
        short8 a = __builtin_bit_cast(short8, stage[abase + ((kk * 4 + quad) ^ ax)]);
        acc0 = MFMA(a, wh[0][kk], acc0);
        acc1 = MFMA(a, wh[1][kk], acc1);
      }
    }
    __syncthreads();                                   // #5 all h ds_reads done

    // ---- gates to LDS: D layout col=lane&15, row(batch)=quad*4+reg ----
#pragma unroll
    for (int r = 0; r < 4; ++r) {
      int row = wave * 16 + quad * 4 + r;
      gf[row * 33 + lm] = acc0[r];
      gf[row * 33 + 16 + lm] = acc1[r];
    }
    __syncthreads();                                   // #6 gates visible

    // ---- epilogue: c/h update for (me, u0), (me, u0+1) ----
    unsigned short* hdst = hb0 + (size_t)((s + 1) & 1) * 32768;
    float hv[2];
#pragma unroll
    for (int rep = 0; rep < 2; ++rep) {
      int u = u0 + rep;
      float gi  = gf[me * 33 + u]      + bsum[0][rep];
      float gfr = gf[me * 33 + 8 + u]  + bsum[1][rep];
      float gg  = gf[me * 33 + 16 + u] + bsum[2][rep];
      float go  = gf[me * 33 + 24 + u] + bsum[3][rep];
      float cn = sigm(gfr) * creg[rep] + sigm(gi) * tanh_fast(gg);
      creg[rep] = cn;
      hv[rep] = sigm(go) * tanh_fast(cn);
    }
    // h slice: sc1 write-through (agent-visible once vmcnt drains at barrier #7)
    unsigned hpack = (unsigned)f2bf(hv[0]) | ((unsigned)f2bf(hv[1]) << 16);
    __hip_atomic_store((unsigned*)(hdst + (size_t)me * 512 + hb + u0), hpack,
                       __ATOMIC_RELAXED, __HIP_MEMORY_SCOPE_AGENT);
    // out slice: plain cached stores (flushed at kernel end)
    float2 ov; ov.x = hv[0]; ov.y = hv[1];
    *(float2*)(out + (size_t)t * 65536 + (size_t)me * 1024 + dir * 512 + hb + u0) = ov;
    hlast[0] = hv[0]; hlast[1] = hv[1];

    __syncthreads();  // #7 drains vmcnt(0): all sc1 h-stores at coherent point; gf reads done
    if (tid == 0)
      __hip_atomic_store(&myflags[jw], s + 1, __ATOMIC_RELAXED, __HIP_MEMORY_SCOPE_AGENT);
  }

  // ---- final hT, cT ----
  float* obase = out + 33554432 + dir * 65536;
  float2 hvf; hvf.x = hlast[0]; hvf.y = hlast[1];
  float2 cvf; cvf.x = creg[0];  cvf.y = creg[1];
  *(float2*)(obase + (size_t)me * 512 + hb + u0) = hvf;
  *(float2*)(obase + 32768 + (size_t)me * 512 + hb + u0) = cvf;
}

extern "C" void kernel_launch(void* const* d_in, const int* in_sizes, int n_in,
                              void* d_out, int out_size, void* d_ws, size_t ws_size,
                              hipStream_t stream) {
  (void)in_sizes; (void)n_in; (void)out_size; (void)ws_size;

  const float* X     = (const float*)d_in[0];
  const float* h0_f  = (const float*)d_in[1];
  const float* c0_f  = (const float*)d_in[2];
  const float* h0_b  = (const float*)d_in[3];
  const float* c0_b  = (const float*)d_in[4];
  const float* Wih_f = (const float*)d_in[5];
  const float* Whh_f = (const float*)d_in[6];
  const float* bih_f = (const float*)d_in[7];
  const float* bhh_f = (const float*)d_in[8];
  const float* Wih_b = (const float*)d_in[9];
  const float* Whh_b = (const float*)d_in[10];
  const float* bih_b = (const float*)d_in[11];
  const float* bhh_b = (const float*)d_in[12];
  float* out = (float*)d_out;

  unsigned short* xbf   = (unsigned short*)d_ws;                         // 33,554,432 B
  unsigned short* hbufs = (unsigned short*)((char*)d_ws + 33554432);     //    262,144 B
  int* flags            = (int*)((char*)d_ws + 33554432 + 262144);       //        512 B

  prep_x<<<16384, 256, 0, stream>>>((const float4*)X, (ushort4*)xbf);
  prep_init<<<256, 256, 0, stream>>>(h0_f, h0_b, hbufs, flags);

  lstm_coop<<<dim3(128), dim3(256), 0, stream>>>(
      xbf, hbufs, flags,
      Wih_f, Whh_f, bih_f, bhh_f, c0_f,
      Wih_b, Whh_b, bih_b, bhh_b, c0_b,
      out);
}